// Round 6
// baseline (965.262 us; speedup 1.0000x reference)
//
#include <hip/hip_runtime.h>
#include <math.h>

// ClassificationBackbone: conv/attn pipeline, fp32 throughout.
// R6: attn — no-LDS split-m flash attention. 128-thr blocks (2 waves = 2
// channel halves, no barriers), R=2 rows/lane, m in 4-lane-groups (16-lane
// broadcast global loads, L1/L2 served), S-way m-split across blocks with
// (num, den) partials in workspace + merge kernel. K/Q packed [Np][8].

#define DEVINL __device__ __forceinline__

DEVINL float selu_f(float x) {
  const float scale = 1.0507009873554805f;
  const float alpha = 1.6732632423543772f;
  return scale * (x > 0.f ? x : alpha * (__expf(x) - 1.f));
}

// ---------------- prep: h = concat([x^0.25/255^0.25, x], batch) -------------
__global__ __launch_bounds__(256) void k_prep(const float* __restrict__ x,
                                              float* __restrict__ h, int n) {
  const float invScale = 0.250244727f;  // 255^-0.25
  for (int i = blockIdx.x * blockDim.x + threadIdx.x; i < n;
       i += gridDim.x * blockDim.x) {
    float v = x[i];
    h[i] = sqrtf(sqrtf(v)) * invScale;
    h[n + i] = v;
  }
}

// ---------------- LDS-tiled conv3x3 (+bias)(+selu)(+avgpool2) ---------------
template <bool POOL, bool DO_SELU, bool DO_BIAS>
__global__ __launch_bounds__(256) void k_conv3x3t(
    const float* __restrict__ in, const float* __restrict__ w,
    const float* __restrict__ bias, float* __restrict__ outA,
    float* __restrict__ outB, int splitB, int Bn, int Cin, int Cout, int IH,
    int IW, int tilesX, int tilesY) {
  constexpr int CI_CHUNK = 5;
  constexpr int ROWF = 36;  // padded LDS row (floats)
  __shared__ __align__(16) float lds[CI_CHUNK * 34 * ROWF];

  const int CH = IH - 2, CW = IW - 2;
  const int OH = POOL ? (CH >> 1) : CH;
  const int OW = POOL ? (CW >> 1) : CW;

  int bid = blockIdx.x;
  const int tX = bid % tilesX; bid /= tilesX;
  const int tY = bid % tilesY; bid /= tilesY;
  const int occ = bid % (Cout >> 1);
  const int b = bid / (Cout >> 1);
  const int oc0 = occ * 2;

  const int tid = threadIdx.x;
  const int ty = tid >> 4, tx = tid & 15;
  const int cy = 2 * ty, cx = 2 * tx;

  const int cy0 = tY * 32, cx0 = tX * 32;
  const long inb = (long)b * Cin * IH * IW;

  float a0[2][2] = {{0.f, 0.f}, {0.f, 0.f}};
  float a1[2][2] = {{0.f, 0.f}, {0.f, 0.f}};

  for (int ci0 = 0; ci0 < Cin; ci0 += CI_CHUNK) {
    const int nch = min(CI_CHUNK, Cin - ci0);
    const int nstage = nch * 34 * 34;
    __syncthreads();
    for (int i = tid; i < nstage; i += 256) {
      const int c = i % 34;
      const int t = i / 34;
      const int r = t % 34;
      const int cl = t / 34;
      const int gy = cy0 + r, gx = cx0 + c;
      float v = 0.f;
      if (gy < IH && gx < IW)
        v = in[inb + ((long)(ci0 + cl) * IH + gy) * IW + gx];
      lds[(cl * 34 + r) * ROWF + c] = v;
    }
    __syncthreads();

    for (int cl = 0; cl < CI_CHUNK; ++cl) {
      const int ci = ci0 + cl;
      if (ci >= Cin) break;
      float pr[4][4];
      const float* base = &lds[(cl * 34 + cy) * ROWF + cx];
#pragma unroll
      for (int r = 0; r < 4; ++r) {
        float2 u0 = *(const float2*)(base + r * ROWF);
        float2 u1 = *(const float2*)(base + r * ROWF + 2);
        pr[r][0] = u0.x; pr[r][1] = u0.y; pr[r][2] = u1.x; pr[r][3] = u1.y;
      }
      const float* wp0 = w + ((long)oc0 * Cin + ci) * 9;
      const float* wp1 = wp0 + (long)Cin * 9;
#pragma unroll
      for (int ky = 0; ky < 3; ++ky)
#pragma unroll
        for (int kx = 0; kx < 3; ++kx) {
          const float w0 = wp0[ky * 3 + kx];
          const float w1 = wp1[ky * 3 + kx];
#pragma unroll
          for (int r = 0; r < 2; ++r)
#pragma unroll
            for (int c = 0; c < 2; ++c) {
              const float v = pr[r + ky][c + kx];
              a0[r][c] = fmaf(w0, v, a0[r][c]);
              a1[r][c] = fmaf(w1, v, a1[r][c]);
            }
        }
    }
  }

  const float b0 = DO_BIAS ? bias[oc0] : 0.f;
  const float b1 = DO_BIAS ? bias[oc0 + 1] : 0.f;

  if (POOL) {
    const int py = tY * 16 + ty, px = tX * 16 + tx;
    if (py < OH && px < OW) {
#pragma unroll
      for (int o = 0; o < 2; ++o) {
        const float bb = o ? b1 : b0;
        float s = 0.f;
#pragma unroll
        for (int r = 0; r < 2; ++r)
#pragma unroll
          for (int c = 0; c < 2; ++c) {
            float v = (o ? a1[r][c] : a0[r][c]) + bb;
            if (DO_SELU) v = selu_f(v);
            s += v;
          }
        const float rv = 0.25f * s;
        const int oc = oc0 + o;
        if (outB != nullptr && b >= splitB)
          outB[(((long)(b - splitB) * Cout + oc) * OH + py) * OW + px] = rv;
        else
          outA[(((long)b * Cout + oc) * OH + py) * OW + px] = rv;
      }
    }
  } else {
#pragma unroll
    for (int o = 0; o < 2; ++o) {
      const float bb = o ? b1 : b0;
      const int oc = oc0 + o;
#pragma unroll
      for (int r = 0; r < 2; ++r)
#pragma unroll
        for (int c = 0; c < 2; ++c) {
          const int oy = cy0 + cy + r, ox = cx0 + cx + c;
          if (oy < OH && ox < OW) {
            float v = (o ? a1[r][c] : a0[r][c]) + bb;
            if (DO_SELU) v = selu_f(v);
            float* dst = (outB != nullptr && b >= splitB)
                             ? &outB[(((long)(b - splitB) * Cout + oc) * OH + oy) * OW + ox]
                             : &outA[(((long)b * Cout + oc) * OH + oy) * OW + ox];
            *dst = v;
          }
        }
    }
  }
}

// ---------------- q/k/v projections -> padded transposed layouts ------------
// qt,kt: [Np][8] (cols d>=D zero; rows n>=N zero); vt: [Np][Cp].
template <int Cp>
__global__ __launch_bounds__(256) void k_qkv3(
    const float* __restrict__ x, const float* __restrict__ wq,
    const float* __restrict__ bq, const float* __restrict__ wk,
    const float* __restrict__ bk, const float* __restrict__ wv,
    const float* __restrict__ bv, float* __restrict__ qt,
    float* __restrict__ kt, float* __restrict__ vt, int Bn, int C, int D,
    int N, int Np) {
  constexpr int KP = 8;
  const int S = Np * (2 * KP + Cp);
  const int total = Bn * S;
  for (int idx = blockIdx.x * blockDim.x + threadIdx.x; idx < total;
       idx += gridDim.x * blockDim.x) {
    const int b = idx / S;
    const int rr = idx % S;
    const float* xb = x + (long)b * C * N;
    const float* w = nullptr;
    const float* bp = nullptr;
    float* dst;
    int n, co, lim;
    if (rr < Np * KP) {
      n = rr / KP; co = rr % KP; lim = D;
      w = wq + co * C; bp = bq;
      dst = qt + ((long)b * Np + n) * KP + co;
    } else if (rr < 2 * Np * KP) {
      const int t = rr - Np * KP;
      n = t / KP; co = t % KP; lim = D;
      w = wk + co * C; bp = bk;
      dst = kt + ((long)b * Np + n) * KP + co;
    } else {
      const int t = rr - 2 * Np * KP;
      n = t / Cp; co = t % Cp; lim = C;
      w = wv + co * C; bp = bv;
      dst = vt + ((long)b * Np + n) * Cp + co;
    }
    if (co < lim && n < N) {
      float a = bp[co];
      for (int ci = 0; ci < C; ++ci) a = fmaf(w[ci], xb[(long)ci * N + n], a);
      *dst = a;
    } else {
      *dst = 0.f;
    }
  }
}

// ---------------- flash attention partials (no LDS, split-m) ----------------
// 128 thr = 2 waves (cg = channel half). lane: g=lane>>4 m-subgroup (0..3),
// r=lane&15; rows n = brow + r + 16k, k=0..1 (32 rows/block). Block handles
// m-slice [s*msz, min(+msz, N)). K/V read straight from global (L2-resident,
// 16-lane broadcast). No __syncthreads. Partials: num[(s*8+b)*Cp+cc][Nr],
// den[(s*8+b)][Nr]. Softmax without max-subtraction is exact here (tiny
// energies, shift-invariant). N must be a multiple of 4 (2304/2116/64 ok).
template <int C, int Chp>
__global__ __launch_bounds__(128) void k_attn6(
    const float* __restrict__ qt, const float* __restrict__ kt,
    const float* __restrict__ vt, float* __restrict__ num,
    float* __restrict__ den, int N, int nbr, int S, int msz, int Np, int Nr) {
  constexpr int KP = 8;
  constexpr int Cp = 2 * Chp;
  constexpr int NV = Chp / 4;
  int bid = blockIdx.x;
  const int s = bid % S; bid /= S;
  const int rb = bid % nbr;
  const int b = bid / nbr;
  const int brow = rb * 32;
  const int tid = threadIdx.x;
  const int lane = tid & 63;
  const int cg = tid >> 6;  // channel half 0/1
  const int g = lane >> 4;  // m subgroup 0..3
  const int r = lane & 15;  // row base

  const float* qb = qt + (long)b * Np * KP;
  const float* kb = kt + (long)b * Np * KP;
  const float* vb = vt + (long)b * Np * Cp;

  float4 q0[2], q1[2];
#pragma unroll
  for (int k = 0; k < 2; ++k) {
    const int n = brow + r + 16 * k;  // n < Nr <= Np always
    q0[k] = *(const float4*)(qb + (long)n * KP);
    q1[k] = *(const float4*)(qb + (long)n * KP + 4);
  }

  float acc[2][Chp];
#pragma unroll
  for (int k = 0; k < 2; ++k)
#pragma unroll
    for (int c = 0; c < Chp; ++c) acc[k][c] = 0.f;
  float sm[2] = {0.f, 0.f};

  const int mstart = s * msz;
  const int mlimit = min(mstart + msz, N);
  for (int m0 = mstart; m0 < mlimit; m0 += 4) {
    const int m = m0 + g;  // < N (N multiple of 4)
    const float4 ka = *(const float4*)(kb + (long)m * KP);
    const float4 kb4 = *(const float4*)(kb + (long)m * KP + 4);
    float4 vv[NV];
    const float4* vp = (const float4*)(vb + (long)m * Cp + cg * Chp);
#pragma unroll
    for (int j = 0; j < NV; ++j) vv[j] = vp[j];
#pragma unroll
    for (int k = 0; k < 2; ++k) {
      float e = q0[k].x * ka.x;
      e = fmaf(q0[k].y, ka.y, e);
      e = fmaf(q0[k].z, ka.z, e);
      e = fmaf(q0[k].w, ka.w, e);
      e = fmaf(q1[k].x, kb4.x, e);
      e = fmaf(q1[k].y, kb4.y, e);
      e = fmaf(q1[k].z, kb4.z, e);
      e = fmaf(q1[k].w, kb4.w, e);
      const float p = __expf(e);
      sm[k] += p;
#pragma unroll
      for (int j = 0; j < NV; ++j) {
        acc[k][4 * j + 0] = fmaf(p, vv[j].x, acc[k][4 * j + 0]);
        acc[k][4 * j + 1] = fmaf(p, vv[j].y, acc[k][4 * j + 1]);
        acc[k][4 * j + 2] = fmaf(p, vv[j].z, acc[k][4 * j + 2]);
        acc[k][4 * j + 3] = fmaf(p, vv[j].w, acc[k][4 * j + 3]);
      }
    }
  }

  // reduce the 4 m-subgroups (lane bits 4,5)
#pragma unroll
  for (int k = 0; k < 2; ++k) {
    sm[k] += __shfl_xor(sm[k], 16, 64);
    sm[k] += __shfl_xor(sm[k], 32, 64);
#pragma unroll
    for (int c = 0; c < Chp; ++c) {
      acc[k][c] += __shfl_xor(acc[k][c], 16, 64);
      acc[k][c] += __shfl_xor(acc[k][c], 32, 64);
    }
  }

  if (g == 0) {
    float* np_ = num + ((long)(s * 8 + b) * Cp + cg * Chp) * Nr;
    float* dp_ = den + (long)(s * 8 + b) * Nr;
#pragma unroll
    for (int k = 0; k < 2; ++k) {
      const int n = brow + r + 16 * k;
      if (n < N) {
#pragma unroll
        for (int c = 0; c < Chp; ++c) np_[(long)c * Nr + n] = acc[k][c];
        if (cg == 0) dp_[n] = sm[k];
      }
    }
  }
}

// ---------------- attention merge: out = x + g * (sum num)/(sum den) --------
__global__ __launch_bounds__(256) void k_attnmerge(
    const float* __restrict__ x, const float* __restrict__ num,
    const float* __restrict__ den, const float* __restrict__ gamma_p,
    float* __restrict__ out, int C, int Cp, int N, int Nr, int S) {
  const float g = gamma_p[0];
  const int total = 8 * C * N;
  for (int idx = blockIdx.x * blockDim.x + threadIdx.x; idx < total;
       idx += gridDim.x * blockDim.x) {
    const int n = idx % N;
    const int t = idx / N;
    const int c = t % C;
    const int b = t / C;
    float a = 0.f, d = 0.f;
    for (int s = 0; s < S; ++s) {
      a += num[((long)(s * 8 + b) * Cp + c) * Nr + n];
      d += den[(long)(s * 8 + b) * Nr + n];
    }
    out[((long)b * C + c) * N + n] =
        fmaf(g, a / d, x[((long)b * C + c) * N + n]);
  }
}

// ---------------- batchnorm stats: mean + rsqrt(var+eps) per channel --------
__global__ __launch_bounds__(256) void k_bnstats(const float* __restrict__ x,
                                                 float* __restrict__ stats,
                                                 int Bn, int C, int HW,
                                                 float eps) {
  int c = blockIdx.x;
  int tid = threadIdx.x;
  int cnt = Bn * HW;
  float s = 0.f, s2 = 0.f;
  for (int i = tid; i < cnt; i += blockDim.x) {
    int b = i / HW, r = i % HW;
    float v = x[((long)b * C + c) * HW + r];
    s += v;
    s2 += v * v;
  }
#pragma unroll
  for (int off = 32; off > 0; off >>= 1) {
    s += __shfl_down(s, off);
    s2 += __shfl_down(s2, off);
  }
  __shared__ float as_[4], as2_[4];
  int wid = tid >> 6;
  if ((tid & 63) == 0) { as_[wid] = s; as2_[wid] = s2; }
  __syncthreads();
  if (tid == 0) {
    float S = 0.f, S2 = 0.f;
#pragma unroll
    for (int ww = 0; ww < 4; ++ww) { S += as_[ww]; S2 += as2_[ww]; }
    float mean = S / (float)cnt;
    float var = S2 / (float)cnt - mean * mean;
    stats[c] = mean;
    stats[C + c] = rsqrtf(var + eps);
  }
}

// ---------------- BN apply + selu (+pool) ----------------
template <bool POOL>
__global__ __launch_bounds__(256) void k_bn_selu(
    const float* __restrict__ x, const float* __restrict__ stats,
    const float* __restrict__ g, const float* __restrict__ beta,
    float* __restrict__ out, int Bn, int C, int IH, int IW) {
  int OH = POOL ? (IH >> 1) : IH;
  int OW = POOL ? (IW >> 1) : IW;
  int total = Bn * C * OH * OW;
  for (int idx = blockIdx.x * blockDim.x + threadIdx.x; idx < total;
       idx += gridDim.x * blockDim.x) {
    int px = idx % OW;
    int t = idx / OW;
    int py = t % OH;
    t /= OH;
    int c = t % C;
    int b = t / C;
    float mean = stats[c], istd = stats[C + c];
    float gg = g[c], bb = beta[c];
    const float* ip = x + ((long)b * C + c) * IH * IW;
    float r;
    if (POOL) {
      int iy = py * 2, ix = px * 2;
      float v00 = selu_f((ip[iy * IW + ix] - mean) * istd * gg + bb);
      float v01 = selu_f((ip[iy * IW + ix + 1] - mean) * istd * gg + bb);
      float v10 = selu_f((ip[(iy + 1) * IW + ix] - mean) * istd * gg + bb);
      float v11 = selu_f((ip[(iy + 1) * IW + ix + 1] - mean) * istd * gg + bb);
      r = 0.25f * (v00 + v01 + v10 + v11);
    } else {
      r = selu_f((ip[py * IW + px] - mean) * istd * gg + bb);
    }
    out[((b * C + c) * OH + py) * OW + px] = r;
  }
}

static inline int gs(int total) { return (total + 255) / 256; }
static inline int cdiv(int a, int b) { return (a + b - 1) / b; }

extern "C" void kernel_launch(void* const* d_in, const int* in_sizes, int n_in,
                              void* d_out, int out_size, void* d_ws,
                              size_t ws_size, hipStream_t stream) {
  const float* x      = (const float*)d_in[0];
  const float* enc_w1 = (const float*)d_in[1];
  const float* enc_b1 = (const float*)d_in[2];
  const float* enc_w2 = (const float*)d_in[3];
  const float* enc_b2 = (const float*)d_in[4];
  const float* a1_wq  = (const float*)d_in[5];
  const float* a1_bq  = (const float*)d_in[6];
  const float* a1_wk  = (const float*)d_in[7];
  const float* a1_bk  = (const float*)d_in[8];
  const float* a1_wv  = (const float*)d_in[9];
  const float* a1_bv  = (const float*)d_in[10];
  const float* a1_g   = (const float*)d_in[11];
  const float* c1_w   = (const float*)d_in[12];
  const float* c1_b   = (const float*)d_in[13];
  const float* a2_wq  = (const float*)d_in[14];
  const float* a2_bq  = (const float*)d_in[15];
  const float* a2_wk  = (const float*)d_in[16];
  const float* a2_bk  = (const float*)d_in[17];
  const float* a2_wv  = (const float*)d_in[18];
  const float* a2_bv  = (const float*)d_in[19];
  const float* a2_g   = (const float*)d_in[20];
  const float* c2_w   = (const float*)d_in[21];
  const float* c2_b   = (const float*)d_in[22];
  const float* c3_w   = (const float*)d_in[23];
  const float* c3_g   = (const float*)d_in[24];
  const float* c3_be  = (const float*)d_in[25];
  const float* c4_w   = (const float*)d_in[26];
  const float* c4_g   = (const float*)d_in[27];
  const float* c4_be  = (const float*)d_in[28];
  const float* a3_wq  = (const float*)d_in[29];
  const float* a3_bq  = (const float*)d_in[30];
  const float* a3_wk  = (const float*)d_in[31];
  const float* a3_bk  = (const float*)d_in[32];
  const float* a3_wv  = (const float*)d_in[33];
  const float* a3_bv  = (const float*)d_in[34];
  const float* a3_g   = (const float*)d_in[35];

  float* out = (float*)d_out;
  float* W = (float*)d_ws;

  // ---- workspace plan (floats, liveness-checked; peak 5,056,320) ----
  float* h    = W;                 // [0, 1920000)
  float* h1   = W + 1920000;       // [1920000, 5056320)
  float* h2   = W;                 // [0, 737280)
  float* xenc = out + 5120;        // (8,40,48,48) direct

  // attn1: Np=Nr=2304, S=4
  float* q1   = W + 737280;        // [737280, 884736)
  float* k1   = W + 884736;        // [884736, 1032192)
  float* v1   = W + 1032192;       // [1032192, 1769472)
  float* num1 = W + 1920000;       // [1920000, 4869120)  4*8*40*2304
  float* den1 = W + 4869120;       // [4869120, 4942848)
  float* at1  = W + 737280;        // [737280, 1474560)   (q/k/v1 dead)
  float* c1o  = W + 4209920;       // [4209920, 5056320)  (num1/den1 dead)

  // attn2: Np=2176, Nr=2116, S=3
  float* q2   = W;                 // [0, 139264)
  float* k2   = W + 139264;        // [139264, 278528)
  float* v2   = W + 278528;        // [278528, 1253376)
  float* num2 = W + 1253376;       // [1253376, 4097280)  3*8*56*2116
  float* den2 = W + 4097280;       // [4097280, 4148064)
  float* at2  = W;                 // [0, 846400)         (q/k/v2 dead)

  float* c2o  = W + 846400;        // [846400, 1001280)
  float* c3o  = W + 1001280;       // [1001280, 1097280)
  float* st3  = W + 1097280;       // 60
  float* c3p  = W + 1098240;       // [1098240, 1122240)
  float* c4o  = W + 1122304;       // [1122304, 1127424)
  float* st4  = W + 1127488;       // 20
  float* c4b  = W + 1127552;       // [1127552, 1132672)
  // attn3: Np=128, Nr=64, S=1
  float* q3   = W + 1132672;       // 8192
  float* k3   = W + 1140864;       // 8192
  float* v3   = W + 1149056;       // 16384
  float* num3 = W + 1165440;       // 8192
  float* den3 = W + 1173632;       // 512

  const int NOSPLIT = 1 << 30;

  // 1. prep
  {
    int n = 8 * 3 * 200 * 200;
    k_prep<<<gs(n), 256, 0, stream>>>(x, h, n);
  }
  // 2. enc conv1 + selu + pool : (16,3,200,200)->(16,20,99,99)
  {
    int tXY = cdiv(99, 16);
    int blocks = 16 * (20 / 2) * tXY * tXY;
    k_conv3x3t<true, true, true><<<blocks, 256, 0, stream>>>(
        h, enc_w1, enc_b1, h1, nullptr, NOSPLIT, 16, 3, 20, 200, 200, tXY, tXY);
  }
  // 3. enc conv2 + selu + pool : (16,20,99,99)->(16,40,48,48); b>=8 -> x_enc
  {
    int tXY = cdiv(48, 16);
    int blocks = 16 * (40 / 2) * tXY * tXY;
    k_conv3x3t<true, true, true><<<blocks, 256, 0, stream>>>(
        h1, enc_w2, enc_b2, h2, xenc, 8, 16, 20, 40, 99, 99, tXY, tXY);
  }
  // 4. attn1 qkv : Cp=40, Np=2304
  {
    int total = 8 * 2304 * (16 + 40);
    k_qkv3<40><<<gs(total), 256, 0, stream>>>(h2, a1_wq, a1_bq, a1_wk, a1_bk,
                                              a1_wv, a1_bv, q1, k1, v1, 8, 40,
                                              5, 2304, 2304);
  }
  // 5. attn1 partials + merge : C=40, Chp=20, S=4
  {
    int nbr = 72, S = 4, msz = 576;
    k_attn6<40, 20><<<8 * nbr * S, 128, 0, stream>>>(q1, k1, v1, num1, den1,
                                                     2304, nbr, S, msz, 2304,
                                                     2304);
    k_attnmerge<<<gs(8 * 40 * 2304), 256, 0, stream>>>(h2, num1, den1, a1_g,
                                                       at1, 40, 40, 2304, 2304,
                                                       S);
  }
  // 6. c1 conv + selu : (8,40,48,48)->(8,50,46,46)
  {
    int tXY = cdiv(46, 32);
    int blocks = 8 * (50 / 2) * tXY * tXY;
    k_conv3x3t<false, true, true><<<blocks, 256, 0, stream>>>(
        at1, c1_w, c1_b, c1o, nullptr, NOSPLIT, 8, 40, 50, 48, 48, tXY, tXY);
  }
  // 7. attn2 qkv : Cp=56, Np=2176
  {
    int total = 8 * 2176 * (16 + 56);
    k_qkv3<56><<<gs(total), 256, 0, stream>>>(c1o, a2_wq, a2_bq, a2_wk, a2_bk,
                                              a2_wv, a2_bv, q2, k2, v2, 8, 50,
                                              6, 2116, 2176);
  }
  // 8. attn2 partials + merge : C=50, Chp=28, S=3
  {
    int nbr = 67, S = 3, msz = 708;
    k_attn6<50, 28><<<8 * nbr * S, 128, 0, stream>>>(q2, k2, v2, num2, den2,
                                                     2116, nbr, S, msz, 2176,
                                                     2116);
    k_attnmerge<<<gs(8 * 50 * 2116), 256, 0, stream>>>(c1o, num2, den2, a2_g,
                                                       at2, 50, 56, 2116, 2116,
                                                       S);
  }
  // 9. c2 conv + selu + pool : (8,50,46,46)->(8,40,22,22)
  {
    int tXY = cdiv(22, 16);
    int blocks = 8 * (40 / 2) * tXY * tXY;
    k_conv3x3t<true, true, true><<<blocks, 256, 0, stream>>>(
        at2, c2_w, c2_b, c2o, nullptr, NOSPLIT, 8, 50, 40, 46, 46, tXY, tXY);
  }
  // 10. c3 conv (no bias, no act) : (8,40,22,22)->(8,30,20,20)
  {
    int tXY = cdiv(20, 32);
    int blocks = 8 * (30 / 2) * tXY * tXY;
    k_conv3x3t<false, false, false><<<blocks, 256, 0, stream>>>(
        c2o, c3_w, nullptr, c3o, nullptr, NOSPLIT, 8, 40, 30, 22, 22, tXY,
        tXY);
  }
  // 11-12. BN(c3) + selu + pool -> (8,30,10,10)
  k_bnstats<<<30, 256, 0, stream>>>(c3o, st3, 8, 30, 400, 1e-5f);
  {
    int total = 8 * 30 * 10 * 10;
    k_bn_selu<true><<<gs(total), 256, 0, stream>>>(c3o, st3, c3_g, c3_be, c3p,
                                                   8, 30, 20, 20);
  }
  // 13. c4 conv : (8,30,10,10)->(8,10,8,8)
  {
    int tXY = cdiv(8, 32);
    int blocks = 8 * (10 / 2) * tXY * tXY;
    k_conv3x3t<false, false, false><<<blocks, 256, 0, stream>>>(
        c3p, c4_w, nullptr, c4o, nullptr, NOSPLIT, 8, 30, 10, 10, 10, tXY,
        tXY);
  }
  // 14-15. BN(c4) + selu
  k_bnstats<<<10, 256, 0, stream>>>(c4o, st4, 8, 10, 64, 1e-5f);
  {
    int total = 8 * 10 * 8 * 8;
    k_bn_selu<false><<<gs(total), 256, 0, stream>>>(c4o, st4, c4_g, c4_be, c4b,
                                                    8, 10, 8, 8);
  }
  // 16. attn3 qkv : Cp=16, Np=128
  {
    int total = 8 * 128 * (16 + 16);
    k_qkv3<16><<<gs(total), 256, 0, stream>>>(c4b, a3_wq, a3_bq, a3_wk, a3_bk,
                                              a3_wv, a3_bv, q3, k3, v3, 8, 10,
                                              1, 64, 128);
  }
  // 17. attn3 partials + merge -> out[0..5120) : C=10, Chp=8, S=1
  {
    int nbr = 2, S = 1, msz = 64;
    k_attn6<10, 8><<<8 * nbr * S, 128, 0, stream>>>(q3, k3, v3, num3, den3, 64,
                                                    nbr, S, msz, 128, 64);
    k_attnmerge<<<gs(8 * 10 * 64), 256, 0, stream>>>(c4b, num3, den3, a3_g,
                                                     out, 10, 16, 64, 64, S);
  }
}